// Round 5
// baseline (170.482 us; speedup 1.0000x reference)
//
#include <hip/hip_runtime.h>

#define N_NODES 100000
#define N_EDGES 800000
#define IN_SIZE 128
#define OUT_SIZE 64

#define GEMM_BLOCKS 512
#define RP_BLOCKS   128
#define N_TILES     (N_NODES / 16)   // 6250 exact

// propagation grid: oct = blockIdx&7 -> XCD (documented %8 round-robin);
// quarter q = oct>>1 (2 XCDs per 16-channel plane, 3.2MB < 4MiB L2).
// chunks of 128 nodes: 782 per quarter; blocks = 8 * 391 = 3128.
#define PROP_CHUNKS 782
#define PROP_BLOCKS (8 * 391)

typedef __attribute__((ext_vector_type(8))) short short8;
typedef __attribute__((ext_vector_type(4))) float f32x4;

__device__ __forceinline__ unsigned short f2bf(float x) {
    unsigned u = __float_as_uint(x);
    u += 0x7FFFu + ((u >> 16) & 1u);          // round-to-nearest-even
    return (unsigned short)(u >> 16);
}
__device__ __forceinline__ unsigned pack2(float lo, float hi) {
    return (unsigned)f2bf(lo) | ((unsigned)f2bf(hi) << 16);
}
__device__ __forceinline__ float bflo(unsigned u) { return __uint_as_float(u << 16); }
__device__ __forceinline__ float bfhi(unsigned u) { return __uint_as_float(u & 0xFFFF0000u); }

// ---------------------------------------------------------------------------
// Kernel 1 (fused): H0 = bf16(data @ W + b) via MFMA, written QUARTER-PLANAR
// (plane q = channels 16q..16q+15, [node][16] bf16 = 32B/node, 3.2MB/plane),
// + CSR rowptr build in trailing blocks.
// GEMM core identical to R4 (passed, ~12-15us): persistent waves, W frags
// once per wave, A inline fp32->bf16, 16x mfma_f32_16x16x32_bf16 per 16-row
// tile, epilogue transpose through wave-private LDS (stride 72 = 2-way banks,
// free). Only the final store addressing changed (plane q = seg>>1).
// ---------------------------------------------------------------------------
__global__ __launch_bounds__(256) void gemm_rowptr_kernel(
    const float* __restrict__ data, const float* __restrict__ W,
    const float* __restrict__ b, const int* __restrict__ tgt,
    unsigned short* __restrict__ H, int* __restrict__ rowptr)
{
    if (blockIdx.x >= GEMM_BLOCKS) {
        int t = (int)(blockIdx.x - GEMM_BLOCKS) * 256 + (int)threadIdx.x;
        for (; t <= N_NODES; t += RP_BLOCKS * 256) {
            int lo = 0, hi = N_EDGES;
            while (lo < hi) {
                const int mid = (lo + hi) >> 1;
                if (tgt[mid] < t) lo = mid + 1; else hi = mid;
            }
            rowptr[t] = lo;
        }
        return;
    }

    __shared__ unsigned short Clds[4][16 * 72];  // 9216 B; wave-private regions

    const int tid  = threadIdx.x;
    const int lane = tid & 63;
    const int wv   = tid >> 6;
    const int quad = lane >> 4;
    const int col  = lane & 15;

    union U8 { short8 v; unsigned short u[8]; };

    // B fragments from global W (fp32 -> bf16); B[k=quad*8+j][n=nt*16+col]
    short8 wb[4][4];
    #pragma unroll
    for (int kc = 0; kc < 4; ++kc) {
        #pragma unroll
        for (int nt = 0; nt < 4; ++nt) {
            U8 t;
            #pragma unroll
            for (int j = 0; j < 8; ++j) {
                const int k = kc * 32 + quad * 8 + j;
                t.u[j] = f2bf(W[k * OUT_SIZE + nt * 16 + col]);
            }
            wb[kc][nt] = t.v;
        }
    }
    float bcol[4];
    #pragma unroll
    for (int nt = 0; nt < 4; ++nt) bcol[nt] = b[nt * 16 + col];

    unsigned short* cl = Clds[wv];
    const int gw = blockIdx.x * 4 + wv;
    uint4* Hq = (uint4*)H;   // plane q node n half h: [q*(N*2) + n*2 + h]

    for (int tile = gw; tile < N_TILES; tile += GEMM_BLOCKS * 4) {
        const int r0 = tile * 16;
        const float* arow = data + (size_t)(r0 + col) * IN_SIZE + quad * 8;

        short8 af[4];
        #pragma unroll
        for (int kc = 0; kc < 4; ++kc) {
            const float4 x0 = *(const float4*)(arow + kc * 32);
            const float4 x1 = *(const float4*)(arow + kc * 32 + 4);
            U8 t;
            t.u[0] = f2bf(x0.x); t.u[1] = f2bf(x0.y);
            t.u[2] = f2bf(x0.z); t.u[3] = f2bf(x0.w);
            t.u[4] = f2bf(x1.x); t.u[5] = f2bf(x1.y);
            t.u[6] = f2bf(x1.z); t.u[7] = f2bf(x1.w);
            af[kc] = t.v;
        }

        f32x4 acc[4];
        #pragma unroll
        for (int nt = 0; nt < 4; ++nt) acc[nt] = (f32x4){0.f, 0.f, 0.f, 0.f};
        #pragma unroll
        for (int kc = 0; kc < 4; ++kc) {
            #pragma unroll
            for (int nt = 0; nt < 4; ++nt)
                acc[nt] = __builtin_amdgcn_mfma_f32_16x16x32_bf16(
                    af[kc], wb[kc][nt], acc[nt], 0, 0, 0);
        }

        // epilogue: bias + bf16 into wave-private LDS (C-layout scatter)
        #pragma unroll
        for (int nt = 0; nt < 4; ++nt) {
            #pragma unroll
            for (int r = 0; r < 4; ++r)
                cl[(quad * 4 + r) * 72 + nt * 16 + col] =
                    f2bf(acc[nt][r] + bcol[nt]);
        }
        // transpose readback -> quarter-planar stores (same-wave LDS ordering)
        #pragma unroll
        for (int p = 0; p < 2; ++p) {
            const int row = p * 8 + (lane >> 3);
            const int seg = lane & 7;             // 8-channel chunk
            const uint4 vv = *(const uint4*)(cl + row * 72 + seg * 8);
            Hq[(size_t)(seg >> 1) * (N_NODES * 2) +
               (size_t)(r0 + row) * 2 + (seg & 1)] = vv;
        }
    }
}

// ---------------------------------------------------------------------------
// Kernel 2/3: one propagation round on quarter-planar bf16.
// out[t] = (in[t] + sum_{e: tgt_e=t} in[src_e]) / (deg+1); 0 if deg==0.
// 2 lanes per node (s = half of the 32B quarter-row); per-lane edge loop,
// unroll-4 with clamped indices + masked fma -> 4 independent 16B gathers in
// flight per lane (256/wave), all from this XCD's L2-resident 3.2MB plane.
// FINAL: fp32 + relu, row-major d_out (64B contiguous per node-quarter);
// else bf16 quarter-planar.
// ---------------------------------------------------------------------------
__device__ __forceinline__ void acc_fma8(float* a, const uint4 v, const float m) {
    a[0] = fmaf(bflo(v.x), m, a[0]); a[1] = fmaf(bfhi(v.x), m, a[1]);
    a[2] = fmaf(bflo(v.y), m, a[2]); a[3] = fmaf(bfhi(v.y), m, a[3]);
    a[4] = fmaf(bflo(v.z), m, a[4]); a[5] = fmaf(bfhi(v.z), m, a[5]);
    a[6] = fmaf(bflo(v.w), m, a[6]); a[7] = fmaf(bfhi(v.w), m, a[7]);
}
__device__ __forceinline__ void acc_add8(float* a, const uint4 v) {
    a[0] += bflo(v.x); a[1] += bfhi(v.x);
    a[2] += bflo(v.y); a[3] += bfhi(v.y);
    a[4] += bflo(v.z); a[5] += bfhi(v.z);
    a[6] += bflo(v.w); a[7] += bfhi(v.w);
}

template <bool FINAL>
__global__ __launch_bounds__(256) void prop_kernel(
    const unsigned short* __restrict__ in, void* __restrict__ outp,
    const int* __restrict__ rowptr, const int* __restrict__ src)
{
    const int tid   = threadIdx.x;
    const int oct   = blockIdx.x & 7;         // -> XCD (round-robin heuristic)
    const int q     = oct >> 1;               // quarter plane for this XCD
    const int chunk = ((int)blockIdx.x >> 3) * 2 + (oct & 1);
    const int s     = tid & 1;                // 16B half of 32B quarter-row
    const int noder = chunk * 128 + (tid >> 1);
    const bool valid = noder < N_NODES;
    const int node  = valid ? noder : N_NODES - 1;

    const int start = rowptr[node];
    const int end   = rowptr[node + 1];
    const int deg   = end - start;

    const uint4* plane = (const uint4*)in + (size_t)q * (N_NODES * 2);
    const uint4 ownq = plane[(size_t)node * 2 + s];

    float acc0[8], acc1[8];
    #pragma unroll
    for (int k = 0; k < 8; ++k) { acc0[k] = 0.f; acc1[k] = 0.f; }

    for (int e = start; e < end; e += 4) {
        const int cm = end - e;                   // >= 1
        const int i1 = e + (cm > 1 ? 1 : 0);
        const int i2 = e + (cm > 2 ? 2 : 0);
        const int i3 = e + (cm > 3 ? 3 : 0);
        const int s0 = src[e];
        const int s1 = src[i1];
        const int s2 = src[i2];
        const int s3 = src[i3];
        const uint4 v0 = plane[(size_t)s0 * 2 + s];
        const uint4 v1 = plane[(size_t)s1 * 2 + s];
        const uint4 v2 = plane[(size_t)s2 * 2 + s];
        const uint4 v3 = plane[(size_t)s3 * 2 + s];
        const float m1 = cm > 1 ? 1.f : 0.f;
        const float m2 = cm > 2 ? 1.f : 0.f;
        const float m3 = cm > 3 ? 1.f : 0.f;
        acc_add8(acc0, v0);
        acc_fma8(acc1, v1, m1);
        acc_fma8(acc0, v2, m2);
        acc_fma8(acc1, v3, m3);
    }

    float o[8];
    if (deg == 0) {
        #pragma unroll
        for (int k = 0; k < 8; ++k) o[k] = 0.f;
    } else {
        acc_add8(acc0, ownq);
        const float inv = 1.0f / (float)(deg + 1);
        #pragma unroll
        for (int k = 0; k < 8; ++k) {
            o[k] = (acc0[k] + acc1[k]) * inv;
            if (FINAL) o[k] = fmaxf(o[k], 0.f);
        }
    }

    if (!valid) return;

    if (FINAL) {
        float* out = (float*)outp + (size_t)node * OUT_SIZE + q * 16 + s * 8;
        float4 lo, hi;
        lo.x = o[0]; lo.y = o[1]; lo.z = o[2]; lo.w = o[3];
        hi.x = o[4]; hi.y = o[5]; hi.z = o[6]; hi.w = o[7];
        *(float4*)out       = lo;
        *(float4*)(out + 4) = hi;
    } else {
        uint4 pv;
        pv.x = pack2(o[0], o[1]);
        pv.y = pack2(o[2], o[3]);
        pv.z = pack2(o[4], o[5]);
        pv.w = pack2(o[6], o[7]);
        ((uint4*)outp)[(size_t)q * (N_NODES * 2) + (size_t)node * 2 + s] = pv;
    }
}

// ---------------------------------------------------------------------------
// Launch
// ---------------------------------------------------------------------------
extern "C" void kernel_launch(void* const* d_in, const int* in_sizes, int n_in,
                              void* d_out, int out_size, void* d_ws, size_t ws_size,
                              hipStream_t stream)
{
    const float* data = (const float*)d_in[0];
    const float* W    = (const float*)d_in[1];
    const float* b    = (const float*)d_in[2];
    const int*   src  = (const int*)d_in[3];
    const int*   tgt  = (const int*)d_in[4];

    // ws: H0 bf16 quarter-planar (12.8MB) | H1 same (12.8MB) | rowptr (400KB)
    unsigned short* H0 = (unsigned short*)d_ws;
    unsigned short* H1 = H0 + (size_t)N_NODES * OUT_SIZE;
    int* rowptr        = (int*)(H1 + (size_t)N_NODES * OUT_SIZE);

    gemm_rowptr_kernel<<<GEMM_BLOCKS + RP_BLOCKS, 256, 0, stream>>>(
        data, W, b, tgt, H0, rowptr);
    prop_kernel<false><<<PROP_BLOCKS, 256, 0, stream>>>(H0, H1, rowptr, src);
    prop_kernel<true ><<<PROP_BLOCKS, 256, 0, stream>>>(H1, d_out, rowptr, src);
}

// Round 6
// 152.257 us; speedup vs baseline: 1.1197x; 1.1197x over previous
//
#include <hip/hip_runtime.h>

#define N_NODES 100000
#define N_EDGES 800000
#define IN_SIZE 128
#define OUT_SIZE 64

#define GEMM_BLOCKS 512
#define RP_BLOCKS   128
#define N_TILES     (N_NODES / 16)   // 6250 exact

typedef __attribute__((ext_vector_type(8))) short short8;
typedef __attribute__((ext_vector_type(4))) float f32x4;

__device__ __forceinline__ unsigned short f2bf(float x) {
    unsigned u = __float_as_uint(x);
    u += 0x7FFFu + ((u >> 16) & 1u);          // round-to-nearest-even
    return (unsigned short)(u >> 16);
}
__device__ __forceinline__ unsigned pack2(float lo, float hi) {
    return (unsigned)f2bf(lo) | ((unsigned)f2bf(hi) << 16);
}
__device__ __forceinline__ float bflo(unsigned u) { return __uint_as_float(u << 16); }
__device__ __forceinline__ float bfhi(unsigned u) { return __uint_as_float(u & 0xFFFF0000u); }

// ---------------------------------------------------------------------------
// Kernel 1 (fused): H0 = bf16(data @ W + b) via MFMA (row-major bf16, 128B
// rows) + CSR rowptr build in trailing blocks. Identical to the R4 version
// (measured ~13us, near its 51MB-read + 13MB-write stream floor).
// ---------------------------------------------------------------------------
__global__ __launch_bounds__(256) void gemm_rowptr_kernel(
    const float* __restrict__ data, const float* __restrict__ W,
    const float* __restrict__ b, const int* __restrict__ tgt,
    unsigned short* __restrict__ H, int* __restrict__ rowptr)
{
    if (blockIdx.x >= GEMM_BLOCKS) {
        int t = (int)(blockIdx.x - GEMM_BLOCKS) * 256 + (int)threadIdx.x;
        for (; t <= N_NODES; t += RP_BLOCKS * 256) {
            int lo = 0, hi = N_EDGES;
            while (lo < hi) {
                const int mid = (lo + hi) >> 1;
                if (tgt[mid] < t) lo = mid + 1; else hi = mid;
            }
            rowptr[t] = lo;
        }
        return;
    }

    __shared__ unsigned short Clds[4][16 * 72];  // 9216 B; wave-private regions

    const int tid  = threadIdx.x;
    const int lane = tid & 63;
    const int wv   = tid >> 6;
    const int quad = lane >> 4;
    const int col  = lane & 15;

    union U8 { short8 v; unsigned short u[8]; };

    // B fragments from global W (fp32 -> bf16); B[k=quad*8+j][n=nt*16+col]
    short8 wb[4][4];
    #pragma unroll
    for (int kc = 0; kc < 4; ++kc) {
        #pragma unroll
        for (int nt = 0; nt < 4; ++nt) {
            U8 t;
            #pragma unroll
            for (int j = 0; j < 8; ++j) {
                const int k = kc * 32 + quad * 8 + j;
                t.u[j] = f2bf(W[k * OUT_SIZE + nt * 16 + col]);
            }
            wb[kc][nt] = t.v;
        }
    }
    float bcol[4];
    #pragma unroll
    for (int nt = 0; nt < 4; ++nt) bcol[nt] = b[nt * 16 + col];

    unsigned short* cl = Clds[wv];
    const int gw = blockIdx.x * 4 + wv;

    for (int tile = gw; tile < N_TILES; tile += GEMM_BLOCKS * 4) {
        const int r0 = tile * 16;
        const float* arow = data + (size_t)(r0 + col) * IN_SIZE + quad * 8;

        short8 af[4];
        #pragma unroll
        for (int kc = 0; kc < 4; ++kc) {
            const float4 x0 = *(const float4*)(arow + kc * 32);
            const float4 x1 = *(const float4*)(arow + kc * 32 + 4);
            U8 t;
            t.u[0] = f2bf(x0.x); t.u[1] = f2bf(x0.y);
            t.u[2] = f2bf(x0.z); t.u[3] = f2bf(x0.w);
            t.u[4] = f2bf(x1.x); t.u[5] = f2bf(x1.y);
            t.u[6] = f2bf(x1.z); t.u[7] = f2bf(x1.w);
            af[kc] = t.v;
        }

        f32x4 acc[4];
        #pragma unroll
        for (int nt = 0; nt < 4; ++nt) acc[nt] = (f32x4){0.f, 0.f, 0.f, 0.f};
        #pragma unroll
        for (int kc = 0; kc < 4; ++kc) {
            #pragma unroll
            for (int nt = 0; nt < 4; ++nt)
                acc[nt] = __builtin_amdgcn_mfma_f32_16x16x32_bf16(
                    af[kc], wb[kc][nt], acc[nt], 0, 0, 0);
        }

        // epilogue: bias + bf16 into wave-private LDS (C-layout scatter)
        #pragma unroll
        for (int nt = 0; nt < 4; ++nt) {
            #pragma unroll
            for (int r = 0; r < 4; ++r)
                cl[(quad * 4 + r) * 72 + nt * 16 + col] =
                    f2bf(acc[nt][r] + bcol[nt]);
        }
        // transpose readback -> coalesced row-major stores (same-wave LDS
        // ordering; compiler inserts lgkmcnt, no barrier needed)
        #pragma unroll
        for (int p = 0; p < 2; ++p) {
            const int row = p * 8 + (lane >> 3);
            const int seg = lane & 7;
            const uint4 vv = *(const uint4*)(cl + row * 72 + seg * 8);
            *(uint4*)(H + (size_t)(r0 + row) * OUT_SIZE + seg * 8) = vv;
        }
    }
}

// ---------------------------------------------------------------------------
// Kernel 2/3: one propagation round on row-major bf16 (128 B/node row).
// out[t] = (in[t] + sum_{e: tgt_e=t} in[src_e]) / (deg+1); 0 if deg==0.
// 8-lane subgroup per node; per batch of 8 edges:
//   - src indices prefetched one batch ahead (software pipeline)
//   - ALL 8 gathers issued branchlessly; invalid slots clamp to slot-0's
//     row (same address -> broadcast, L1-hot) with weight 0.
// Regime: LLC random-gather BW (~3.4 TB/s, 102 MB/round); these trims attack
// the latency component of short-degree nodes (deg<=8: single batch).
// ---------------------------------------------------------------------------
__device__ __forceinline__ void acc_fma8(float* a, const uint4 v, const float m) {
    a[0] = fmaf(bflo(v.x), m, a[0]); a[1] = fmaf(bfhi(v.x), m, a[1]);
    a[2] = fmaf(bflo(v.y), m, a[2]); a[3] = fmaf(bfhi(v.y), m, a[3]);
    a[4] = fmaf(bflo(v.z), m, a[4]); a[5] = fmaf(bfhi(v.z), m, a[5]);
    a[6] = fmaf(bflo(v.w), m, a[6]); a[7] = fmaf(bfhi(v.w), m, a[7]);
}
__device__ __forceinline__ void acc_add8(float* a, const uint4 v) {
    a[0] += bflo(v.x); a[1] += bfhi(v.x);
    a[2] += bflo(v.y); a[3] += bfhi(v.y);
    a[4] += bflo(v.z); a[5] += bfhi(v.z);
    a[6] += bflo(v.w); a[7] += bfhi(v.w);
}

template <bool FINAL>
__global__ __launch_bounds__(256) void prop_kernel(
    const unsigned short* __restrict__ in, void* __restrict__ outp,
    const int* __restrict__ rowptr, const int* __restrict__ src)
{
    const int tid   = threadIdx.x;
    const int lane  = tid & 63;
    const int s     = lane & 7;     // 16B chunk within 128B row
    const int lbase = lane & 56;    // subgroup base lane
    const int node  = blockIdx.x * 32 + (tid >> 3);

    const int start = rowptr[node];
    const int end   = rowptr[node + 1];
    const int deg   = end - start;

    const uint4* inq = (const uint4*)in;    // 8 chunks per row
    const uint4 ownq = inq[(size_t)node * 8 + s];

    float acc0[8], acc1[8];
    #pragma unroll
    for (int k = 0; k < 8; ++k) { acc0[k] = 0.f; acc1[k] = 0.f; }

    if (deg > 0) {
        // cooperative src load for first batch (clamped in-bounds)
        int li = start + s;
        int sv = src[li < end ? li : start];

        for (int base = start; base < end; base += 8) {
            // prefetch next batch's src indices during this batch's gathers
            int svn = 0;
            const int nbase = base + 8;
            if (nbase < end) {
                const int lj = nbase + s;
                svn = src[lj < end ? lj : nbase];
            }

            const int rem = end - base;   // >= 1
            // broadcast 8 src indices; invalid slots fall back to slot 0's
            // src (same row -> L1 broadcast) with weight 0
            const int b0 = __shfl(sv, lbase + 0, 64);
            const int s1 = __shfl(sv, lbase + 1, 64);
            const int s2 = __shfl(sv, lbase + 2, 64);
            const int s3 = __shfl(sv, lbase + 3, 64);
            const int s4 = __shfl(sv, lbase + 4, 64);
            const int s5 = __shfl(sv, lbase + 5, 64);
            const int s6 = __shfl(sv, lbase + 6, 64);
            const int s7 = __shfl(sv, lbase + 7, 64);

            const uint4 v0 = inq[(size_t)b0 * 8 + s];
            const uint4 v1 = inq[(size_t)(rem > 1 ? s1 : b0) * 8 + s];
            const uint4 v2 = inq[(size_t)(rem > 2 ? s2 : b0) * 8 + s];
            const uint4 v3 = inq[(size_t)(rem > 3 ? s3 : b0) * 8 + s];
            const uint4 v4 = inq[(size_t)(rem > 4 ? s4 : b0) * 8 + s];
            const uint4 v5 = inq[(size_t)(rem > 5 ? s5 : b0) * 8 + s];
            const uint4 v6 = inq[(size_t)(rem > 6 ? s6 : b0) * 8 + s];
            const uint4 v7 = inq[(size_t)(rem > 7 ? s7 : b0) * 8 + s];

            acc_add8(acc0, v0);
            acc_fma8(acc1, v1, rem > 1 ? 1.f : 0.f);
            acc_fma8(acc0, v2, rem > 2 ? 1.f : 0.f);
            acc_fma8(acc1, v3, rem > 3 ? 1.f : 0.f);
            acc_fma8(acc0, v4, rem > 4 ? 1.f : 0.f);
            acc_fma8(acc1, v5, rem > 5 ? 1.f : 0.f);
            acc_fma8(acc0, v6, rem > 6 ? 1.f : 0.f);
            acc_fma8(acc1, v7, rem > 7 ? 1.f : 0.f);

            sv = svn;
        }
    }

    float o[8];
    if (deg == 0) {
        #pragma unroll
        for (int k = 0; k < 8; ++k) o[k] = 0.f;
    } else {
        acc_add8(acc0, ownq);
        const float inv = 1.0f / (float)(deg + 1);
        #pragma unroll
        for (int k = 0; k < 8; ++k) {
            o[k] = (acc0[k] + acc1[k]) * inv;
            if (FINAL) o[k] = fmaxf(o[k], 0.f);
        }
    }

    if (FINAL) {
        float* out = (float*)outp;
        float4 lo, hi;
        lo.x = o[0]; lo.y = o[1]; lo.z = o[2]; lo.w = o[3];
        hi.x = o[4]; hi.y = o[5]; hi.z = o[6]; hi.w = o[7];
        *(float4*)(out + (size_t)node * OUT_SIZE + s * 8)     = lo;
        *(float4*)(out + (size_t)node * OUT_SIZE + s * 8 + 4) = hi;
    } else {
        uint4 pv;
        pv.x = pack2(o[0], o[1]);
        pv.y = pack2(o[2], o[3]);
        pv.z = pack2(o[4], o[5]);
        pv.w = pack2(o[6], o[7]);
        ((uint4*)outp)[(size_t)node * 8 + s] = pv;
    }
}

// ---------------------------------------------------------------------------
// Launch
// ---------------------------------------------------------------------------
extern "C" void kernel_launch(void* const* d_in, const int* in_sizes, int n_in,
                              void* d_out, int out_size, void* d_ws, size_t ws_size,
                              hipStream_t stream)
{
    const float* data = (const float*)d_in[0];
    const float* W    = (const float*)d_in[1];
    const float* b    = (const float*)d_in[2];
    const int*   src  = (const int*)d_in[3];
    const int*   tgt  = (const int*)d_in[4];

    // ws: H0 bf16 (12.8MB) | H1 bf16 (12.8MB) | rowptr (400KB)
    unsigned short* H0 = (unsigned short*)d_ws;
    unsigned short* H1 = H0 + (size_t)N_NODES * OUT_SIZE;
    int* rowptr        = (int*)(H1 + (size_t)N_NODES * OUT_SIZE);

    gemm_rowptr_kernel<<<GEMM_BLOCKS + RP_BLOCKS, 256, 0, stream>>>(
        data, W, b, tgt, H0, rowptr);
    prop_kernel<false><<<N_NODES / 32, 256, 0, stream>>>(H0, H1, rowptr, src);
    prop_kernel<true ><<<N_NODES / 32, 256, 0, stream>>>(H1, d_out, rowptr, src);
}

// Round 7
// 149.756 us; speedup vs baseline: 1.1384x; 1.0167x over previous
//
#include <hip/hip_runtime.h>

#define N_NODES 100000
#define N_EDGES 800000
#define IN_SIZE 128
#define OUT_SIZE 64

#define GEMM_BLOCKS 512
#define RP_BLOCKS   128
#define N_TILES     (N_NODES / 16)   // 6250 exact
#define PROP_BLOCKS ((N_NODES + 63) / 64)  // 64 nodes/block, 4 lanes/node

typedef __attribute__((ext_vector_type(8))) short short8;
typedef __attribute__((ext_vector_type(4))) float f32x4;

__device__ __forceinline__ unsigned short f2bf(float x) {
    unsigned u = __float_as_uint(x);
    u += 0x7FFFu + ((u >> 16) & 1u);          // round-to-nearest-even
    return (unsigned short)(u >> 16);
}

// int8 row layout convention (both H buffers): row = 16 dwords; dword d's
// byte b holds channel (d + 16*b), stored BIASED (u = q + 128).
// Per-row fp32 dequant scale in a separate array: val = scale * (u - 128).

// ---------------------------------------------------------------------------
// Kernel 1 (fused): H0 = int8_rowscale(data @ W + b) via MFMA + CSR rowptr.
// MFMA core identical to R4/R6 (~13us). Epilogue: per-row absmax via in-lane
// max over nt + shfl_xor(1,2,4,8) across the 16 col-lanes of the quad, then
// biased-uint8 quantize, pack nt-bytes into dwords (channel d+16b convention
// falls out naturally: byte nt of dword col = channel nt*16+col), transpose
// through wave-private LDS (stride 20 dwords: 2-way banks = free), store
// 64B rows as 4x uint4.
// ---------------------------------------------------------------------------
__global__ __launch_bounds__(256) void gemm_rowptr_kernel(
    const float* __restrict__ data, const float* __restrict__ W,
    const float* __restrict__ b, const int* __restrict__ tgt,
    uint4* __restrict__ H, float* __restrict__ Hs, int* __restrict__ rowptr)
{
    if (blockIdx.x >= GEMM_BLOCKS) {
        int t = (int)(blockIdx.x - GEMM_BLOCKS) * 256 + (int)threadIdx.x;
        for (; t <= N_NODES; t += RP_BLOCKS * 256) {
            int lo = 0, hi = N_EDGES;
            while (lo < hi) {
                const int mid = (lo + hi) >> 1;
                if (tgt[mid] < t) lo = mid + 1; else hi = mid;
            }
            rowptr[t] = lo;
        }
        return;
    }

    __shared__ unsigned Clds[4][16 * 20];  // per-wave 1280B regions

    const int tid  = threadIdx.x;
    const int lane = tid & 63;
    const int wv   = tid >> 6;
    const int quad = lane >> 4;
    const int col  = lane & 15;

    union U8 { short8 v; unsigned short u[8]; };

    // B fragments from global W (fp32 -> bf16); B[k=quad*8+j][n=nt*16+col]
    short8 wb[4][4];
    #pragma unroll
    for (int kc = 0; kc < 4; ++kc) {
        #pragma unroll
        for (int nt = 0; nt < 4; ++nt) {
            U8 t;
            #pragma unroll
            for (int j = 0; j < 8; ++j) {
                const int k = kc * 32 + quad * 8 + j;
                t.u[j] = f2bf(W[k * OUT_SIZE + nt * 16 + col]);
            }
            wb[kc][nt] = t.v;
        }
    }
    float bcol[4];
    #pragma unroll
    for (int nt = 0; nt < 4; ++nt) bcol[nt] = b[nt * 16 + col];

    unsigned* cl = Clds[wv];
    const int gw = blockIdx.x * 4 + wv;

    for (int tile = gw; tile < N_TILES; tile += GEMM_BLOCKS * 4) {
        const int r0 = tile * 16;
        const float* arow = data + (size_t)(r0 + col) * IN_SIZE + quad * 8;

        short8 af[4];
        #pragma unroll
        for (int kc = 0; kc < 4; ++kc) {
            const float4 x0 = *(const float4*)(arow + kc * 32);
            const float4 x1 = *(const float4*)(arow + kc * 32 + 4);
            U8 t;
            t.u[0] = f2bf(x0.x); t.u[1] = f2bf(x0.y);
            t.u[2] = f2bf(x0.z); t.u[3] = f2bf(x0.w);
            t.u[4] = f2bf(x1.x); t.u[5] = f2bf(x1.y);
            t.u[6] = f2bf(x1.z); t.u[7] = f2bf(x1.w);
            af[kc] = t.v;
        }

        f32x4 acc[4];
        #pragma unroll
        for (int nt = 0; nt < 4; ++nt) acc[nt] = (f32x4){0.f, 0.f, 0.f, 0.f};
        #pragma unroll
        for (int kc = 0; kc < 4; ++kc) {
            #pragma unroll
            for (int nt = 0; nt < 4; ++nt)
                acc[nt] = __builtin_amdgcn_mfma_f32_16x16x32_bf16(
                    af[kc], wb[kc][nt], acc[nt], 0, 0, 0);
        }

        // epilogue: +bias, per-row absmax, biased-uint8 quantize
        // C/D layout: channel nt*16+col, row quad*4+reg
        float v[4][4];   // [nt][r]
        #pragma unroll
        for (int nt = 0; nt < 4; ++nt)
            #pragma unroll
            for (int r = 0; r < 4; ++r)
                v[nt][r] = acc[nt][r] + bcol[nt];

        float rmax[4];
        #pragma unroll
        for (int r = 0; r < 4; ++r) {
            float m = fabsf(v[0][r]);
            m = fmaxf(m, fabsf(v[1][r]));
            m = fmaxf(m, fabsf(v[2][r]));
            m = fmaxf(m, fabsf(v[3][r]));
            m = fmaxf(m, __shfl_xor(m, 1, 64));
            m = fmaxf(m, __shfl_xor(m, 2, 64));
            m = fmaxf(m, __shfl_xor(m, 4, 64));
            m = fmaxf(m, __shfl_xor(m, 8, 64));
            rmax[r] = m;
        }
        if (col < 4)
            Hs[r0 + quad * 4 + col] = rmax[col] * (1.f / 127.f);

        #pragma unroll
        for (int r = 0; r < 4; ++r) {
            const float inv = rmax[r] > 0.f ? 127.f / rmax[r] : 0.f;
            const unsigned u0 = (unsigned)(int)rintf(v[0][r] * inv + 128.f);
            const unsigned u1 = (unsigned)(int)rintf(v[1][r] * inv + 128.f);
            const unsigned u2 = (unsigned)(int)rintf(v[2][r] * inv + 128.f);
            const unsigned u3 = (unsigned)(int)rintf(v[3][r] * inv + 128.f);
            cl[(quad * 4 + r) * 20 + col] =
                u0 | (u1 << 8) | (u2 << 16) | (u3 << 24);
        }

        // transpose readback (wave-private LDS, no barrier): 64B row stores
        {
            const int row = lane >> 2;
            const int seg = lane & 3;
            const uint4 vv = *(const uint4*)(cl + row * 20 + seg * 4);
            H[(size_t)(r0 + row) * 4 + seg] = vv;
        }
    }
}

// ---------------------------------------------------------------------------
// Kernel 2/3: one propagation round on int8 per-row-scale rows (64B/row).
// out[t] = (in[t] + sum in[src_e]) / (deg+1); 0 if deg==0.
// 4-lane subgroup per node (s = 16B chunk = 16 channels); batches of 8 edges
// issued branchlessly (invalid slots clamp to edge0, scale weight 0).
// Biased trick: acc += c_j * u; sumS += c_j; val = (acc - 128*sumS)/(deg+1).
// Non-FINAL: requantize (row absmax via shfl_xor(1,2)) -> int8 + scale.
// FINAL: fp32 + relu, un-permute channels through block LDS -> coalesced out.
// ---------------------------------------------------------------------------
#define ACC16(vv, c)                                                        \
    {                                                                        \
        const unsigned* _w = (const unsigned*)&(vv);                         \
        _Pragma("unroll")                                                    \
        for (int _d = 0; _d < 4; ++_d) {                                     \
            _Pragma("unroll")                                                \
            for (int _b = 0; _b < 4; ++_b)                                   \
                acc[_d * 4 + _b] = fmaf(                                     \
                    (float)((_w[_d] >> (8 * _b)) & 255u), (c), acc[_d*4+_b]);\
        }                                                                    \
    }

template <bool FINAL>
__global__ __launch_bounds__(256) void prop_kernel(
    const uint4* __restrict__ inq, const float* __restrict__ insc,
    void* __restrict__ outp, float* __restrict__ outsc,
    const int* __restrict__ rowptr, const int* __restrict__ src)
{
    const int tid   = threadIdx.x;
    const int lane  = tid & 63;
    const int s     = lane & 3;     // 16B chunk (dwords s*4..s*4+3)
    const int lbase = lane & 60;    // subgroup base lane
    const int noder = blockIdx.x * 64 + (tid >> 2);
    const bool valid = noder < N_NODES;
    const int node  = valid ? noder : N_NODES - 1;

    const int start = rowptr[node];
    const int end   = rowptr[node + 1];
    const int deg   = end - start;

    const uint4 ownq = inq[(size_t)node * 4 + s];
    const float owns = insc[node];

    float acc[16];
    #pragma unroll
    for (int k = 0; k < 16; ++k) acc[k] = 0.f;
    float sumS = 0.f;

    if (deg > 0) {
        for (int base = start; base < end; base += 8) {
            const int rem = end - base;
            const int liA = base + s;
            const int svA = src[liA < end ? liA : base];
            int svB = 0;
            if (base + 4 < end) {
                const int liB = base + 4 + s;
                svB = src[liB < end ? liB : base + 4];
            }
            const int e0 = __shfl(svA, lbase + 0, 64);
            const int e1 = __shfl(svA, lbase + 1, 64);
            const int e2 = __shfl(svA, lbase + 2, 64);
            const int e3 = __shfl(svA, lbase + 3, 64);
            const int e4 = __shfl(svB, lbase + 0, 64);
            const int e5 = __shfl(svB, lbase + 1, 64);
            const int e6 = __shfl(svB, lbase + 2, 64);
            const int e7 = __shfl(svB, lbase + 3, 64);

            const int i1 = rem > 1 ? e1 : e0;
            const int i2 = rem > 2 ? e2 : e0;
            const int i3 = rem > 3 ? e3 : e0;
            const int i4 = rem > 4 ? e4 : e0;
            const int i5 = rem > 5 ? e5 : e0;
            const int i6 = rem > 6 ? e6 : e0;
            const int i7 = rem > 7 ? e7 : e0;

            const uint4 v0 = inq[(size_t)e0 * 4 + s];
            const uint4 v1 = inq[(size_t)i1 * 4 + s];
            const uint4 v2 = inq[(size_t)i2 * 4 + s];
            const uint4 v3 = inq[(size_t)i3 * 4 + s];
            const uint4 v4 = inq[(size_t)i4 * 4 + s];
            const uint4 v5 = inq[(size_t)i5 * 4 + s];
            const uint4 v6 = inq[(size_t)i6 * 4 + s];
            const uint4 v7 = inq[(size_t)i7 * 4 + s];

            const float c0 = insc[e0];
            const float c1 = rem > 1 ? insc[i1] : 0.f;
            const float c2 = rem > 2 ? insc[i2] : 0.f;
            const float c3 = rem > 3 ? insc[i3] : 0.f;
            const float c4 = rem > 4 ? insc[i4] : 0.f;
            const float c5 = rem > 5 ? insc[i5] : 0.f;
            const float c6 = rem > 6 ? insc[i6] : 0.f;
            const float c7 = rem > 7 ? insc[i7] : 0.f;

            sumS += c0 + c1 + c2 + c3 + c4 + c5 + c6 + c7;
            ACC16(v0, c0); ACC16(v1, c1); ACC16(v2, c2); ACC16(v3, c3);
            ACC16(v4, c4); ACC16(v5, c5); ACC16(v6, c6); ACC16(v7, c7);
        }
        // own contribution
        ACC16(ownq, owns);
        sumS += owns;
    }

    float val[16];
    if (deg == 0) {
        #pragma unroll
        for (int k = 0; k < 16; ++k) val[k] = 0.f;
    } else {
        const float invm  = 1.0f / (float)(deg + 1);
        const float bias  = 128.f * sumS;
        #pragma unroll
        for (int k = 0; k < 16; ++k) {
            val[k] = (acc[k] - bias) * invm;
            if (FINAL) val[k] = fmaxf(val[k], 0.f);
        }
    }

    if (FINAL) {
        // un-permute: channel of val[d*4+b] is (s*4+d) + 16*b
        __shared__ float T[64 * 68];
        const int nl = tid >> 2;
        #pragma unroll
        for (int d = 0; d < 4; ++d)
            #pragma unroll
            for (int bb = 0; bb < 4; ++bb)
                T[nl * 68 + (s * 4 + d) + 16 * bb] = val[d * 4 + bb];
        __syncthreads();
        float* out = (float*)outp;
        const int nb = blockIdx.x * 64;
        #pragma unroll
        for (int p = 0; p < 4; ++p) {
            const int pos = p * 1024 + tid * 4;  // dword index in 64x64 tile
            const int n   = pos >> 6;
            const int ch  = pos & 63;
            if (nb + n < N_NODES) {
                const float4 vv = *(const float4*)(T + n * 68 + ch);
                *(float4*)(out + (size_t)(nb + n) * OUT_SIZE + ch) = vv;
            }
        }
    } else {
        // requantize: row absmax across 16 in-lane + 4-lane subgroup
        float m = 0.f;
        #pragma unroll
        for (int k = 0; k < 16; ++k) m = fmaxf(m, fabsf(val[k]));
        m = fmaxf(m, __shfl_xor(m, 1, 64));
        m = fmaxf(m, __shfl_xor(m, 2, 64));
        const float invq = m > 0.f ? 127.f / m : 0.f;
        uint4 pv;
        unsigned* pw = (unsigned*)&pv;
        #pragma unroll
        for (int d = 0; d < 4; ++d) {
            const unsigned u0 = (unsigned)(int)rintf(val[d * 4 + 0] * invq + 128.f);
            const unsigned u1 = (unsigned)(int)rintf(val[d * 4 + 1] * invq + 128.f);
            const unsigned u2 = (unsigned)(int)rintf(val[d * 4 + 2] * invq + 128.f);
            const unsigned u3 = (unsigned)(int)rintf(val[d * 4 + 3] * invq + 128.f);
            pw[d] = u0 | (u1 << 8) | (u2 << 16) | (u3 << 24);
        }
        if (valid) {
            ((uint4*)outp)[(size_t)node * 4 + s] = pv;
            if (s == 0) outsc[node] = m * (1.f / 127.f);
        }
    }
}

// ---------------------------------------------------------------------------
// Launch
// ---------------------------------------------------------------------------
extern "C" void kernel_launch(void* const* d_in, const int* in_sizes, int n_in,
                              void* d_out, int out_size, void* d_ws, size_t ws_size,
                              hipStream_t stream)
{
    const float* data = (const float*)d_in[0];
    const float* W    = (const float*)d_in[1];
    const float* b    = (const float*)d_in[2];
    const int*   src  = (const int*)d_in[3];
    const int*   tgt  = (const int*)d_in[4];

    // ws: H0 int8 (6.4MB) | H1 int8 (6.4MB) | H0s | H1s | rowptr
    char*  base   = (char*)d_ws;
    uint4* H0     = (uint4*)base;
    uint4* H1     = (uint4*)(base + (size_t)N_NODES * OUT_SIZE);
    float* H0s    = (float*)(base + 2 * (size_t)N_NODES * OUT_SIZE);
    float* H1s    = H0s + N_NODES;
    int*   rowptr = (int*)(H1s + N_NODES);

    gemm_rowptr_kernel<<<GEMM_BLOCKS + RP_BLOCKS, 256, 0, stream>>>(
        data, W, b, tgt, H0, H0s, rowptr);
    prop_kernel<false><<<PROP_BLOCKS, 256, 0, stream>>>(
        H0, H0s, (void*)H1, H1s, rowptr, src);
    prop_kernel<true ><<<PROP_BLOCKS, 256, 0, stream>>>(
        H1, H1s, d_out, nullptr, rowptr, src);
}